// Round 13
// baseline (531.105 us; speedup 1.0000x reference)
//
#include <hip/hip_runtime.h>
#include <cstdint>
#include <cstddef>

// ---------------------------------------------------------------------------
// LateJoinSAGE round 13: round 12 (514us) +
//  (a) layer-0 fp8 row split: M8[node][128B] (aligned, 2 line-touches) +
//      E8[node][32B] (3.2MB, per-XCD-L2-resident) — cuts L2-miss gather
//      traffic from 3 to ~2 lines/row.
//  (b) k_gemm RF=2: 2 row-fragments per wave (128 rows/block) — halves
//      per-block weight streaming and block count.
// ---------------------------------------------------------------------------

#define LRELU(v) ((v) > 0.f ? (v) : 0.01f * (v))

typedef __attribute__((ext_vector_type(8))) short bf16x8;
typedef __attribute__((ext_vector_type(4))) float f32x4;
typedef float floatx2 __attribute__((ext_vector_type(2)));

union U4B8 {
    uint4 u;
    bf16x8 b;
};

__device__ inline unsigned bf16_rn(float x) {
    unsigned u = __float_as_uint(x);
    return (u + 0x7fffu + ((u >> 16) & 1u)) >> 16;
}
__device__ inline unsigned pack2(float lo, float hi) {
    return bf16_rn(lo) | (bf16_rn(hi) << 16);
}
__device__ inline float2 up2(unsigned v) {
    return make_float2(__uint_as_float(v << 16), __uint_as_float(v & 0xffff0000u));
}

// ---------------- fp8 e4m3 helpers ----------------
__device__ inline float e4m3_to_f32(unsigned b) {
    float v = __uint_as_float((b & 0x7fu) << 20) * 0x1p120f;
    return __uint_as_float(__float_as_uint(v) | ((b & 0x80u) << 24));
}

template <bool HI>
__device__ inline floatx2 fp8x2_dec(unsigned v) {
#if __has_builtin(__builtin_amdgcn_cvt_pk_f32_fp8)
    return __builtin_amdgcn_cvt_pk_f32_fp8((int)v, HI);
#else
    unsigned w = HI ? (v >> 16) : v;
    floatx2 r;
    r.x = e4m3_to_f32(w & 0xffu);
    r.y = e4m3_to_f32((w >> 8) & 0xffu);
    return r;
#endif
}

__device__ inline unsigned char f32_to_e4m3_sw(float f) {
    unsigned u = __float_as_uint(f);
    unsigned s = (u >> 24) & 0x80u;
    float a = fabsf(f);
    if (a > 448.f) a = 448.f;
    unsigned b = __float_as_uint(a);
    int exp = (int)(b >> 23) - 127;
    unsigned r;
    if (exp < -9) {
        r = 0;
    } else if (exp >= -6) {
        unsigned m = b & 0x7fffffu;
        unsigned keep = m >> 20;
        unsigned rb = (m >> 19) & 1u;
        unsigned sticky = (m & 0x7ffffu) ? 1u : 0u;
        unsigned inc = rb & (sticky | (keep & 1u));
        unsigned em = (((unsigned)(exp + 7)) << 3) | keep;
        em += inc;
        if (em > 0x7eu) em = 0x7eu;
        r = em;
    } else {
        float t = a * 512.f;
        int q = (int)(t + 0.5f);
        r = (q > 7) ? 0x08u : (unsigned)q;
    }
    return (unsigned char)(r | s);
}

__device__ inline unsigned fp8x4_enc(float f0, float f1, float f2, float f3) {
#if __has_builtin(__builtin_amdgcn_cvt_pk_fp8_f32)
    int pk = __builtin_amdgcn_cvt_pk_fp8_f32(f0, f1, 0, false);
    pk = __builtin_amdgcn_cvt_pk_fp8_f32(f2, f3, pk, true);
    return (unsigned)pk;
#else
    return (unsigned)f32_to_e4m3_sw(f0) | ((unsigned)f32_to_e4m3_sw(f1) << 8) |
           ((unsigned)f32_to_e4m3_sw(f2) << 16) | ((unsigned)f32_to_e4m3_sw(f3) << 24);
#endif
}

// --- x0 concat -> bf16 (stride 160) + fp8 split: M8[n][32u] + E8[n][8u] ----
__global__ void k_concat(const float* __restrict__ nf, const int* __restrict__ opc,
                         const float* __restrict__ emb, unsigned* __restrict__ x0,
                         unsigned* __restrict__ m8, unsigned* __restrict__ e8,
                         int n) {
    int idx = blockIdx.x * 256 + threadIdx.x;
    if (idx >= n * 40) return;
    int node = idx / 40;
    int u = idx - node * 40;
    float f[4];
#pragma unroll
    for (int j = 0; j < 4; j++) {
        int ft = 4 * u + j;
        float v = 0.f;
        if (ft < 140) v = nf[(size_t)node * 140 + ft];
        else if (ft < 148) v = emb[opc[node] * 8 + (ft - 140)];
        f[j] = v;
    }
    ((uint2*)x0)[idx] = make_uint2(pack2(f[0], f[1]), pack2(f[2], f[3]));
    unsigned enc = fp8x4_enc(f[0], f[1], f[2], f[3]);
    if (u < 32) m8[(size_t)node * 32 + u] = enc;
    else        e8[(size_t)node * 8 + (u - 32)] = enc;
}

// ---------------- bf16 (stride 32 uints) -> fp8 (16 uints) ----------------
__global__ void k_cvt8(const unsigned* __restrict__ xb, unsigned* __restrict__ x8,
                       int n) {
    int idx = blockIdx.x * 256 + threadIdx.x;
    if (idx >= n * 16) return;
    uint2 v = ((const uint2*)xb)[idx];
    float2 ab = up2(v.x);
    float2 cd = up2(v.y);
    x8[idx] = fp8x4_enc(ab.x, ab.y, cd.x, cd.y);
}

// ---------------- bucketed CSR build ----------------
__global__ __launch_bounds__(256) void k_bh(const int* __restrict__ ei, int E,
                                            int NBUCK, int* __restrict__ bcnt) {
    __shared__ int h[1024];
    int t = threadIdx.x;
    for (int i = t; i < 1024; i += 256) h[i] = 0;
    __syncthreads();
    int e0 = blockIdx.x * 4096, e1 = min(E, e0 + 4096);
    for (int e = e0 + t; e < e1; e += 256) {
        int a = ei[2 * e], b = ei[2 * e + 1];
        atomicAdd(&h[b >> 7], 1);
        atomicAdd(&h[a >> 7], 1);
    }
    __syncthreads();
    for (int i = t; i < NBUCK; i += 256)
        if (h[i]) atomicAdd(&bcnt[i], h[i]);
}

__global__ void k_bscan(const int* __restrict__ bcnt, int NBUCK,
                        int* __restrict__ bo, int* __restrict__ bfill) {
    __shared__ int sm[1024];
    int t = threadIdx.x;
    int v = (t < NBUCK) ? bcnt[t] : 0;
    sm[t] = v;
    __syncthreads();
    for (int off = 1; off < 1024; off <<= 1) {
        int u = 0;
        if (t >= off) u = sm[t - off];
        __syncthreads();
        sm[t] += u;
        __syncthreads();
    }
    if (t < NBUCK) {
        int ex = sm[t] - v;
        bo[t] = ex;
        bfill[t] = ex;
    }
    if (t == NBUCK - 1) bo[NBUCK] = sm[t];
}

__global__ __launch_bounds__(256) void k_bscatter(const int* __restrict__ ei, int E,
                                                  int* __restrict__ bfill,
                                                  uint2* __restrict__ pairs) {
    __shared__ int hist[1024], lbo[1024], gb[1024], cur[1024];
    __shared__ int wsum[4];
    __shared__ int stageD[8192];
    __shared__ int stageS[8192];
    int t = threadIdx.x;
    for (int i = t; i < 1024; i += 256) hist[i] = 0;
    __syncthreads();
    int e0 = blockIdx.x * 4096, e1 = min(E, e0 + 4096);
    for (int e = e0 + t; e < e1; e += 256) {
        int a = ei[2 * e], b = ei[2 * e + 1];
        atomicAdd(&hist[b >> 7], 1);
        atomicAdd(&hist[a >> 7], 1);
    }
    __syncthreads();
    int b4 = t * 4;
    int c0 = hist[b4], c1 = hist[b4 + 1], c2 = hist[b4 + 2], c3 = hist[b4 + 3];
    int ms = c0 + c1 + c2 + c3;
    int lane = t & 63, wv = t >> 6;
    int v = ms;
#pragma unroll
    for (int off = 1; off < 64; off <<= 1) {
        int u = __shfl_up(v, off, 64);
        if (lane >= off) v += u;
    }
    if (lane == 63) wsum[wv] = v;
    __syncthreads();
    int wb = 0;
    for (int i = 0; i < wv; i++) wb += wsum[i];
    int ex = wb + v - ms;
    lbo[b4] = ex;
    lbo[b4 + 1] = ex + c0;
    lbo[b4 + 2] = ex + c0 + c1;
    lbo[b4 + 3] = ex + c0 + c1 + c2;
    if (c0) gb[b4 + 0] = atomicAdd(&bfill[b4 + 0], c0);
    if (c1) gb[b4 + 1] = atomicAdd(&bfill[b4 + 1], c1);
    if (c2) gb[b4 + 2] = atomicAdd(&bfill[b4 + 2], c2);
    if (c3) gb[b4 + 3] = atomicAdd(&bfill[b4 + 3], c3);
    cur[b4] = 0;
    cur[b4 + 1] = 0;
    cur[b4 + 2] = 0;
    cur[b4 + 3] = 0;
    __syncthreads();
    for (int e = e0 + t; e < e1; e += 256) {
        int a = ei[2 * e], b = ei[2 * e + 1];
        int bk = b >> 7;
        int r = atomicAdd(&cur[bk], 1);
        int p = lbo[bk] + r;
        stageD[p] = b;
        stageS[p] = a;
        bk = a >> 7;
        r = atomicAdd(&cur[bk], 1);
        p = lbo[bk] + r;
        stageD[p] = a;
        stageS[p] = b;
    }
    __syncthreads();
    int tot = 2 * (e1 - e0);
    for (int i = t; i < tot; i += 256) {
        int d = stageD[i];
        int bk = d >> 7;
        pairs[gb[bk] + (i - lbo[bk])] = make_uint2((unsigned)d, (unsigned)stageS[i]);
    }
}

__global__ __launch_bounds__(256) void k_bfinal(const uint2* __restrict__ pairs,
                                                const int* __restrict__ bo,
                                                int* __restrict__ rp,
                                                int* __restrict__ csr,
                                                float* __restrict__ invd,
                                                int N, int NBUCK) {
    __shared__ int hist[128], ls[128], cur[128];
    __shared__ unsigned outS[6144];
    int t = threadIdx.x;
    int bk = blockIdx.x;
    int n0 = bk << 7;
    int nn = min(128, N - n0);
    int base = bo[bk], cnt = bo[bk + 1] - base;
    if (t < 128) {
        hist[t] = 0;
        cur[t] = 0;
    }
    __syncthreads();
    for (int i = t; i < cnt; i += 256) atomicAdd(&hist[(int)pairs[base + i].x - n0], 1);
    __syncthreads();
    if (t == 0) {
        int run = 0;
        for (int i = 0; i < 128; i++) {
            ls[i] = run;
            run += hist[i];
        }
    }
    __syncthreads();
    if (t < nn) {
        int node = n0 + t;
        rp[node] = base + ls[t];
        invd[node] = 1.0f / fmaxf((float)hist[t], 1.0f);
    }
    if (bk == NBUCK - 1 && t == 0) rp[N] = base + cnt;
    bool inl = (cnt <= 6144);
    for (int i = t; i < cnt; i += 256) {
        uint2 pr = pairs[base + i];
        int loc = (int)pr.x - n0;
        int r = atomicAdd(&cur[loc], 1);
        int pos = ls[loc] + r;
        if (inl) outS[pos] = pr.y;
        else csr[base + pos] = (int)pr.y;
    }
    __syncthreads();
    if (inl)
        for (int i = t; i < cnt; i += 256) csr[base + i] = (int)outS[i];
}

// ------- layer-0 aggregation: M8 (128B rows, 2 lines) + E8 (32B, L2-hot) ---
__global__ __launch_bounds__(256) void k_agg160(
    const unsigned* __restrict__ m8, const unsigned* __restrict__ e8,
    const int* __restrict__ rp, const int* __restrict__ csr,
    const float* __restrict__ invd, unsigned* __restrict__ agg, int n) {
    int wave = threadIdx.x >> 6;
    int l = threadIdx.x & 63;
    int node = blockIdx.x * 4 + wave;
    if (node >= n) return;
    int p = l & 31;
    int h = l >> 5;
    int eg = l >> 3;
    int eq = l & 7;
    float am[4] = {0.f, 0.f, 0.f, 0.f};
    float ae[4] = {0.f, 0.f, 0.f, 0.f};
    int s = rp[node], e2 = rp[node + 1];
    int j = s;
    for (; j + 8 <= e2; j += 8) {
#pragma unroll
        for (int i = 0; i < 4; i++) {
            int u = csr[j + 2 * i + h];
            unsigned v = m8[(size_t)u * 32 + p];
            floatx2 lo = fp8x2_dec<false>(v);
            floatx2 hi = fp8x2_dec<true>(v);
            am[0] += lo.x;
            am[1] += lo.y;
            am[2] += hi.x;
            am[3] += hi.y;
        }
        int ue = csr[j + eg];
        unsigned v = e8[(size_t)ue * 8 + eq];
        floatx2 lo = fp8x2_dec<false>(v);
        floatx2 hi = fp8x2_dec<true>(v);
        ae[0] += lo.x;
        ae[1] += lo.y;
        ae[2] += hi.x;
        ae[3] += hi.y;
    }
    for (; j < e2; j++) {
        int u = csr[j];
        if (l < 32) {
            unsigned v = m8[(size_t)u * 32 + p];
            floatx2 lo = fp8x2_dec<false>(v);
            floatx2 hi = fp8x2_dec<true>(v);
            am[0] += lo.x;
            am[1] += lo.y;
            am[2] += hi.x;
            am[3] += hi.y;
        } else if (l < 40) {
            unsigned v = e8[(size_t)u * 8 + eq];
            floatx2 lo = fp8x2_dec<false>(v);
            floatx2 hi = fp8x2_dec<true>(v);
            ae[0] += lo.x;
            ae[1] += lo.y;
            ae[2] += hi.x;
            ae[3] += hi.y;
        }
    }
#pragma unroll
    for (int r = 0; r < 4; r++) am[r] += __shfl_xor(am[r], 32, 64);
#pragma unroll
    for (int r = 0; r < 4; r++) {
        ae[r] += __shfl_xor(ae[r], 8, 64);
        ae[r] += __shfl_xor(ae[r], 16, 64);
        ae[r] += __shfl_xor(ae[r], 32, 64);
    }
    float iv = invd[node];
    unsigned* row = agg + (size_t)node * 80;
    if (l < 32)
        ((uint2*)row)[p] = make_uint2(pack2(am[0] * iv, am[1] * iv),
                                      pack2(am[2] * iv, am[3] * iv));
    if (l < 8)
        ((uint2*)(row + 64))[eq] = make_uint2(pack2(ae[0] * iv, ae[1] * iv),
                                              pack2(ae[2] * iv, ae[3] * iv));
}

// ---------------- 64-dim aggregation from fp8 rows (16 uints = 1 line) -----
__global__ __launch_bounds__(256) void k_agg64_8(
    const unsigned* __restrict__ x8, const int* __restrict__ rp,
    const int* __restrict__ csr, const float* __restrict__ invd,
    unsigned* __restrict__ agg, int n) {
    int wave = threadIdx.x >> 6;
    int l = threadIdx.x & 63;
    int node = blockIdx.x * 4 + wave;
    if (node >= n) return;
    int p = l & 15;
    int g = l >> 4;
    float a[4] = {0.f, 0.f, 0.f, 0.f};
    int s = rp[node], e2 = rp[node + 1];
    int j = s;
    for (; j + 16 <= e2; j += 16) {
        unsigned v[4];
#pragma unroll
        for (int i = 0; i < 4; i++) {
            int u = csr[j + 4 * i + g];
            v[i] = x8[(size_t)u * 16 + p];
        }
#pragma unroll
        for (int i = 0; i < 4; i++) {
            floatx2 lo = fp8x2_dec<false>(v[i]);
            floatx2 hi = fp8x2_dec<true>(v[i]);
            a[0] += lo.x;
            a[1] += lo.y;
            a[2] += hi.x;
            a[3] += hi.y;
        }
    }
    for (; j + 8 <= e2; j += 8) {
        int u0 = csr[j + g];
        int u1 = csr[j + 4 + g];
        unsigned v0 = x8[(size_t)u0 * 16 + p];
        unsigned v1 = x8[(size_t)u1 * 16 + p];
        floatx2 lo0 = fp8x2_dec<false>(v0);
        floatx2 hi0 = fp8x2_dec<true>(v0);
        floatx2 lo1 = fp8x2_dec<false>(v1);
        floatx2 hi1 = fp8x2_dec<true>(v1);
        a[0] += lo0.x + lo1.x;
        a[1] += lo0.y + lo1.y;
        a[2] += hi0.x + hi1.x;
        a[3] += hi0.y + hi1.y;
    }
    for (; j < e2; j += 4) {
        if (j + g < e2) {
            int u = csr[j + g];
            unsigned v = x8[(size_t)u * 16 + p];
            floatx2 lo = fp8x2_dec<false>(v);
            floatx2 hi = fp8x2_dec<true>(v);
            a[0] += lo.x;
            a[1] += lo.y;
            a[2] += hi.x;
            a[3] += hi.y;
        }
    }
#pragma unroll
    for (int r = 0; r < 4; r++) {
        a[r] += __shfl_xor(a[r], 16, 64);
        a[r] += __shfl_xor(a[r], 32, 64);
    }
    if (l < 16) {
        float iv = invd[node];
        ((uint2*)(agg + (size_t)node * 32))[p] =
            make_uint2(pack2(a[0] * iv, a[1] * iv), pack2(a[2] * iv, a[3] * iv));
    }
}

// ---------------- weight pre-pack into B-fragment order --------------------
template <int KS, int KSH, int CT, int C>
__global__ void k_prep(const float* __restrict__ W1, const float* __restrict__ W2,
                       int K1, int K2, uint4* __restrict__ Wp) {
    int idx = blockIdx.x * 256 + threadIdx.x;
    if (idx >= CT * KS * 64) return;
    int l = idx & 63;
    int ks = (idx >> 6) % KS;
    int ct = idx / (KS * 64);
    int col = ct * 16 + (l & 15);
    int kbase = ks * 32 + (l >> 4) * 8;
    unsigned short v[8];
#pragma unroll
    for (int j = 0; j < 8; j++) {
        int k = kbase + j;
        float f = 0.f;
        if (col < C) {
            if (k < KSH * 32) {
                if (k < K1) f = W1[(size_t)k * C + col];
            } else {
                int k2 = k - KSH * 32;
                if (k2 < K2) f = W2[(size_t)k2 * C + col];
            }
        }
        v[j] = (unsigned short)bf16_rn(f);
    }
    uint4 o;
    o.x = v[0] | ((unsigned)v[1] << 16);
    o.y = v[2] | ((unsigned)v[3] << 16);
    o.z = v[4] | ((unsigned)v[5] << 16);
    o.w = v[6] | ((unsigned)v[7] << 16);
    Wp[idx] = o;
}

// ------ MFMA GEMM, RF row-fragments/wave: out = post([A|B] @ Wp + bias) ----
template <int KS, int KSH, int CT, int C, int OST, int NORM, int ACT, int OUTF,
          int RF>
__global__ __launch_bounds__(256) void k_gemm(
    const uint4* __restrict__ A, const uint4* __restrict__ Bb,
    const uint4* __restrict__ Wp, const float* __restrict__ bias,
    void* __restrict__ outv, int n) {
    int l = threadIdx.x & 63;
    int wv = threadIdx.x >> 6;
    constexpr int WROWS = 16 * RF;
    int rb = blockIdx.x * (4 * WROWS) + wv * WROWS;
    int koct = l >> 4;
    const int strideU = KSH * 4;
    size_t baseA[RF];
#pragma unroll
    for (int rf = 0; rf < RF; rf++) {
        int rowA = rb + rf * 16 + (l & 15);
        if (rowA >= n) rowA = n - 1;
        baseA[rf] = (size_t)rowA * strideU + koct;
    }

    f32x4 acc[RF][CT];
#pragma unroll
    for (int rf = 0; rf < RF; rf++)
#pragma unroll
        for (int ct = 0; ct < CT; ct++) acc[rf][ct] = (f32x4){0.f, 0.f, 0.f, 0.f};

#pragma unroll
    for (int ks = 0; ks < KS; ks++) {
        U4B8 a[RF];
#pragma unroll
        for (int rf = 0; rf < RF; rf++)
            a[rf].u = (ks < KSH) ? A[baseA[rf] + ks * 4]
                                 : Bb[baseA[rf] + (ks - KSH) * 4];
#pragma unroll
        for (int ct = 0; ct < CT; ct++) {
            U4B8 b;
            b.u = Wp[(ct * KS + ks) * 64 + l];
#pragma unroll
            for (int rf = 0; rf < RF; rf++)
                acc[rf][ct] = __builtin_amdgcn_mfma_f32_16x16x32_bf16(
                    a[rf].b, b.b, acc[rf][ct], 0, 0, 0);
        }
    }

    int cid = l & 15;
    int grp = l >> 4;
#pragma unroll
    for (int rf = 0; rf < RF; rf++) {
#pragma unroll
        for (int ct = 0; ct < CT; ct++) {
            int col = ct * 16 + cid;
            float bv = (col < C) ? bias[col] : 0.f;
#pragma unroll
            for (int r = 0; r < 4; r++) acc[rf][ct][r] += bv;
        }

        if (NORM) {
            float ss[4];
#pragma unroll
            for (int r = 0; r < 4; r++) {
                ss[r] = 0.f;
#pragma unroll
                for (int ct = 0; ct < CT; ct++) ss[r] += acc[rf][ct][r] * acc[rf][ct][r];
            }
#pragma unroll
            for (int off = 1; off < 16; off <<= 1) {
#pragma unroll
                for (int r = 0; r < 4; r++) ss[r] += __shfl_xor(ss[r], off, 64);
            }
#pragma unroll
            for (int r = 0; r < 4; r++) {
                float sc = 1.0f / fmaxf(sqrtf(ss[r]), 1e-12f);
#pragma unroll
                for (int ct = 0; ct < CT; ct++) acc[rf][ct][r] *= sc;
            }
        }

        if (ACT) {
#pragma unroll
            for (int ct = 0; ct < CT; ct++)
#pragma unroll
                for (int r = 0; r < 4; r++) acc[rf][ct][r] = LRELU(acc[rf][ct][r]);
        }

#pragma unroll
        for (int r = 0; r < 4; r++) {
            int row = rb + rf * 16 + grp * 4 + r;
            if (row >= n) continue;
            if (OUTF) {
                float* o = (float*)outv;
#pragma unroll
                for (int ct = 0; ct < CT; ct++) {
                    int col = ct * 16 + cid;
                    if (col < OST) o[(size_t)row * OST + col] = acc[rf][ct][r];
                }
            } else {
                unsigned short* o = (unsigned short*)outv;
#pragma unroll
                for (int ct = 0; ct < CT; ct++) {
                    int col = ct * 16 + cid;
                    if (col < OST)
                        o[(size_t)row * OST + col] = (unsigned short)bf16_rn(acc[rf][ct][r]);
                }
            }
        }
    }
}

// ---------------- global add-pool: wave per 64 rows, coalesced -------------
__global__ __launch_bounds__(256) void k_pool(const float* __restrict__ x,
                                              const int* __restrict__ batch,
                                              float* __restrict__ g, int n) {
    __shared__ float sm[8][64];
    __shared__ int sb[8];
    int lane = threadIdx.x & 63;
    int wv = threadIdx.x >> 6;
    int base = blockIdx.x * 256 + wv * 64;
    float a0 = 0.f, a1 = 0.f;
    int b0 = -1, b1 = -1;
    int end = (base + 64 < n) ? base + 64 : n;
    for (int row = base; row < end; row++) {
        int bg = batch[row];
        float v = x[(size_t)row * 64 + lane];
        if (b0 < 0) b0 = bg;
        if (bg == b0) a0 += v;
        else { if (b1 < 0) b1 = bg; a1 += v; }
    }
    sm[wv * 2 + 0][lane] = a0;
    sm[wv * 2 + 1][lane] = a1;
    if (lane == 0) {
        sb[wv * 2 + 0] = b0;
        sb[wv * 2 + 1] = b1;
    }
    __syncthreads();
    if (wv == 0) {
        float c0 = 0.f, c1 = 0.f;
        int d0 = -1, d1 = -1;
#pragma unroll
        for (int s = 0; s < 8; s++) {
            int bg = sb[s];
            if (bg < 0) continue;
            float v = sm[s][lane];
            if (d0 < 0) d0 = bg;
            if (bg == d0) c0 += v;
            else { if (d1 < 0) d1 = bg; c1 += v; }
        }
        if (d0 >= 0) atomicAdd(&g[d0 * 64 + lane], c0);
        if (d1 >= 0) atomicAdd(&g[d1 * 64 + lane], c1);
    }
}

// ---------------- post MLP ----------------
__global__ void k_post1(const float* __restrict__ g, const float* __restrict__ cf,
                        const int* __restrict__ ncfg, const float* __restrict__ w1,
                        const float* __restrict__ b1, float* __restrict__ z,
                        int BC, int B) {
    int idx = blockIdx.x * 256 + threadIdx.x;
    if (idx >= BC * 64) return;
    int row = idx >> 6, c = idx & 63;
    int gsum = 0, gid = B - 1;
    for (int b2 = 0; b2 < B; b2++) {
        int ns = ncfg[b2];
        if (row < gsum + ns) { gid = b2; break; }
        gsum += ns;
    }
    float acc = b1[c];
#pragma unroll 4
    for (int k = 0; k < 64; k++) acc += g[gid * 64 + k] * w1[k * 64 + c];
#pragma unroll 4
    for (int k = 0; k < 24; k++) acc += cf[(size_t)row * 24 + k] * w1[(64 + k) * 64 + c];
    z[idx] = LRELU(acc);
}

__global__ void k_post2(const float* __restrict__ z, const float* __restrict__ w2,
                        const float* __restrict__ b2, float* __restrict__ out, int BC) {
    int row = blockIdx.x * 4 + (threadIdx.x >> 6);
    if (row >= BC) return;
    int c = threadIdx.x & 63;
    float v = z[(size_t)row * 64 + c] * w2[c];
#pragma unroll
    for (int off = 32; off > 0; off >>= 1) v += __shfl_xor(v, off, 64);
    if (c == 0) out[row] = v + b2[0];
}

// ---------------------------------------------------------------------------
extern "C" void kernel_launch(void* const* d_in, const int* in_sizes, int n_in,
                              void* d_out, int out_size, void* d_ws, size_t ws_size,
                              hipStream_t stream) {
    const float* node_feat = (const float*)d_in[0];
    const int*   opcode    = (const int*)d_in[1];
    const int*   ei        = (const int*)d_in[2];
    const float* cf        = (const float*)d_in[3];
    const int*   ncfg      = (const int*)d_in[4];
    const int*   batch     = (const int*)d_in[5];
    const float* emb       = (const float*)d_in[6];
    const float* wl0 = (const float*)d_in[7];
    const float* bl0 = (const float*)d_in[8];
    const float* wr0 = (const float*)d_in[9];
    const float* lw0 = (const float*)d_in[10];
    const float* lb0 = (const float*)d_in[11];
    const float* wl1 = (const float*)d_in[12];
    const float* bl1 = (const float*)d_in[13];
    const float* wr1 = (const float*)d_in[14];
    const float* lw1 = (const float*)d_in[15];
    const float* lb1 = (const float*)d_in[16];
    const float* wl2 = (const float*)d_in[17];
    const float* bl2 = (const float*)d_in[18];
    const float* wr2 = (const float*)d_in[19];
    const float* lw2 = (const float*)d_in[20];
    const float* lb2 = (const float*)d_in[21];
    const float* pw1 = (const float*)d_in[22];
    const float* pb1 = (const float*)d_in[23];
    const float* pw2 = (const float*)d_in[24];
    const float* pb2 = (const float*)d_in[25];

    const int N  = in_sizes[0] / 140;
    const int E  = in_sizes[2] / 2;
    const int B  = in_sizes[4];
    const int BC = in_sizes[3] / 24;
    const int NBUCK = (N + 127) >> 7;

    char* w = (char*)d_ws;
    auto alloc = [&](size_t bytes) {
        void* p = (void*)w;
        w += (bytes + 255) & ~(size_t)255;
        return p;
    };
    int*      bcnt     = (int*)alloc(1024 * 4);
    int*      bo       = (int*)alloc(1025 * 4);
    int*      bfill    = (int*)alloc(1024 * 4);
    uint2*    pairs    = (uint2*)alloc((size_t)2 * E * 8);   // dead after k_bfinal
    int*      rp       = (int*)alloc((size_t)(N + 1) * 4);
    float*    invd     = (float*)alloc((size_t)N * 4);
    int*      csr      = (int*)alloc((size_t)2 * E * 4);
    unsigned* X0       = (unsigned*)alloc((size_t)N * 80 * 4);   // bf16, stride 160
    unsigned* AG0      = (unsigned*)alloc((size_t)N * 80 * 4);
    unsigned* H0       = (unsigned*)alloc((size_t)N * 80 * 4);
    unsigned* T0       = (unsigned*)alloc((size_t)N * 32 * 4);   // bf16, stride 64
    unsigned* T1       = (unsigned*)alloc((size_t)N * 32 * 4);
    unsigned* T2       = (unsigned*)alloc((size_t)N * 32 * 4);
    unsigned* G8       = (unsigned*)alloc((size_t)N * 16 * 4);   // fp8 64-dim gather buf
    float*    X3F      = (float*)alloc((size_t)N * 64 * 4);      // final x, f32
    float*    gbuf     = (float*)alloc((size_t)B * 64 * 4);
    float*    zp       = (float*)alloc((size_t)BC * 64 * 4);
    uint4*    Wp0h     = (uint4*)alloc((size_t)10 * 10 * 64 * 16);
    uint4*    Wp0l     = (uint4*)alloc((size_t)4 * 10 * 64 * 16);
    uint4*    Wp1h     = (uint4*)alloc((size_t)4 * 4 * 64 * 16);
    uint4*    Wp1l     = (uint4*)alloc((size_t)4 * 4 * 64 * 16);
    uint4*    Wp2h     = (uint4*)alloc((size_t)4 * 4 * 64 * 16);
    uint4*    Wp2l     = (uint4*)alloc((size_t)4 * 4 * 64 * 16);
    // fp8 x0 split copy (M8: N*32u = 12.8MB, E8: N*8u = 3.2MB) aliases pairs
    // (25.6MB), dead once k_bfinal has run (k_concat launches after it).
    unsigned* M8       = (unsigned*)pairs;
    unsigned* E8       = M8 + (size_t)N * 32;
    (void)ws_size; (void)n_in; (void)out_size;

    (void)hipMemsetAsync(bcnt, 0, 1024 * 4, stream);
    (void)hipMemsetAsync(gbuf, 0, (size_t)B * 64 * 4, stream);

    // weight pre-pack (tiny)
    k_prep<10, 5, 10, 148><<<(6400 + 255) / 256, 256, 0, stream>>>(wl0, wr0, 148, 148, Wp0h);
    k_prep<10, 5, 4, 64><<<(2560 + 255) / 256, 256, 0, stream>>>(lw0, lw0 + 148 * 64, 148, 148, Wp0l);
    k_prep<4, 2, 4, 64><<<4, 256, 0, stream>>>(wl1, wr1, 64, 64, Wp1h);
    k_prep<4, 2, 4, 64><<<4, 256, 0, stream>>>(lw1, lw1 + 64 * 64, 64, 64, Wp1l);
    k_prep<4, 2, 4, 64><<<4, 256, 0, stream>>>(wl2, wr2, 64, 64, Wp2h);
    k_prep<4, 2, 4, 64><<<4, 256, 0, stream>>>(lw2, lw2 + 64 * 64, 64, 64, Wp2l);

    // bucketed CSR build (before k_concat: M8/E8 alias pairs)
    const int EB = (E + 4095) / 4096;
    k_bh<<<EB, 256, 0, stream>>>(ei, E, NBUCK, bcnt);
    k_bscan<<<1, 1024, 0, stream>>>(bcnt, NBUCK, bo, bfill);
    k_bscatter<<<EB, 256, 0, stream>>>(ei, E, bfill, pairs);
    k_bfinal<<<NBUCK, 256, 0, stream>>>(pairs, bo, rp, csr, invd, N, NBUCK);

    k_concat<<<(N * 40 + 255) / 256, 256, 0, stream>>>(node_feat, opcode, emb, X0, M8, E8, N);

    const int AGG_GRID   = (N + 3) / 4;
    const int GEMM_GRID2 = (N + 127) / 128;
    const int CVT_GRID   = (N * 16 + 255) / 256;

    // ---- layer 0 ----
    k_agg160<<<AGG_GRID, 256, 0, stream>>>(M8, E8, rp, csr, invd, AG0, N);
    k_gemm<10, 5, 10, 148, 160, 1, 0, 0, 2><<<GEMM_GRID2, 256, 0, stream>>>(
        (const uint4*)AG0, (const uint4*)X0, Wp0h, bl0, H0, N);
    k_gemm<10, 5, 4, 64, 64, 0, 1, 0, 2><<<GEMM_GRID2, 256, 0, stream>>>(
        (const uint4*)H0, (const uint4*)X0, Wp0l, lb0, T0, N);

    // ---- layer 1 ----
    k_cvt8<<<CVT_GRID, 256, 0, stream>>>(T0, G8, N);
    k_agg64_8<<<AGG_GRID, 256, 0, stream>>>(G8, rp, csr, invd, T1, N);
    k_gemm<4, 2, 4, 64, 64, 1, 0, 0, 2><<<GEMM_GRID2, 256, 0, stream>>>(
        (const uint4*)T1, (const uint4*)T0, Wp1h, bl1, T2, N);
    k_gemm<4, 2, 4, 64, 64, 0, 1, 0, 2><<<GEMM_GRID2, 256, 0, stream>>>(
        (const uint4*)T2, (const uint4*)T0, Wp1l, lb1, T1, N);

    // ---- layer 2 ----
    k_cvt8<<<CVT_GRID, 256, 0, stream>>>(T1, G8, N);
    k_agg64_8<<<AGG_GRID, 256, 0, stream>>>(G8, rp, csr, invd, T0, N);
    k_gemm<4, 2, 4, 64, 64, 1, 0, 0, 2><<<GEMM_GRID2, 256, 0, stream>>>(
        (const uint4*)T0, (const uint4*)T1, Wp2h, bl2, T2, N);
    k_gemm<4, 2, 4, 64, 64, 0, 1, 1, 2><<<GEMM_GRID2, 256, 0, stream>>>(
        (const uint4*)T2, (const uint4*)T1, Wp2l, lb2, X3F, N);

    // pool + post MLP
    k_pool<<<(N + 255) / 256, 256, 0, stream>>>(X3F, batch, gbuf, N);
    k_post1<<<(BC * 64 + 255) / 256, 256, 0, stream>>>(gbuf, cf, ncfg, pw1, pb1, zp, BC, B);
    k_post2<<<(BC + 3) / 4, 256, 0, stream>>>(zp, pw2, pb2, (float*)d_out, BC);
}

// Round 14
// 507.037 us; speedup vs baseline: 1.0475x; 1.0475x over previous
//
#include <hip/hip_runtime.h>
#include <cstdint>
#include <cstddef>

// ---------------------------------------------------------------------------
// LateJoinSAGE round 14: round 13's agg path (M8/E8 fp8 split: 128B aligned
// main rows + 3.2MB L2-resident ext) + round 12's RF=1 GEMMs (64-row blocks;
// RF=2 cost ~20us via VGPR pressure + tail quantization).
// ---------------------------------------------------------------------------

#define LRELU(v) ((v) > 0.f ? (v) : 0.01f * (v))

typedef __attribute__((ext_vector_type(8))) short bf16x8;
typedef __attribute__((ext_vector_type(4))) float f32x4;
typedef float floatx2 __attribute__((ext_vector_type(2)));

union U4B8 {
    uint4 u;
    bf16x8 b;
};

__device__ inline unsigned bf16_rn(float x) {
    unsigned u = __float_as_uint(x);
    return (u + 0x7fffu + ((u >> 16) & 1u)) >> 16;
}
__device__ inline unsigned pack2(float lo, float hi) {
    return bf16_rn(lo) | (bf16_rn(hi) << 16);
}
__device__ inline float2 up2(unsigned v) {
    return make_float2(__uint_as_float(v << 16), __uint_as_float(v & 0xffff0000u));
}

// ---------------- fp8 e4m3 helpers ----------------
__device__ inline float e4m3_to_f32(unsigned b) {
    float v = __uint_as_float((b & 0x7fu) << 20) * 0x1p120f;
    return __uint_as_float(__float_as_uint(v) | ((b & 0x80u) << 24));
}

template <bool HI>
__device__ inline floatx2 fp8x2_dec(unsigned v) {
#if __has_builtin(__builtin_amdgcn_cvt_pk_f32_fp8)
    return __builtin_amdgcn_cvt_pk_f32_fp8((int)v, HI);
#else
    unsigned w = HI ? (v >> 16) : v;
    floatx2 r;
    r.x = e4m3_to_f32(w & 0xffu);
    r.y = e4m3_to_f32((w >> 8) & 0xffu);
    return r;
#endif
}

__device__ inline unsigned char f32_to_e4m3_sw(float f) {
    unsigned u = __float_as_uint(f);
    unsigned s = (u >> 24) & 0x80u;
    float a = fabsf(f);
    if (a > 448.f) a = 448.f;
    unsigned b = __float_as_uint(a);
    int exp = (int)(b >> 23) - 127;
    unsigned r;
    if (exp < -9) {
        r = 0;
    } else if (exp >= -6) {
        unsigned m = b & 0x7fffffu;
        unsigned keep = m >> 20;
        unsigned rb = (m >> 19) & 1u;
        unsigned sticky = (m & 0x7ffffu) ? 1u : 0u;
        unsigned inc = rb & (sticky | (keep & 1u));
        unsigned em = (((unsigned)(exp + 7)) << 3) | keep;
        em += inc;
        if (em > 0x7eu) em = 0x7eu;
        r = em;
    } else {
        float t = a * 512.f;
        int q = (int)(t + 0.5f);
        r = (q > 7) ? 0x08u : (unsigned)q;
    }
    return (unsigned char)(r | s);
}

__device__ inline unsigned fp8x4_enc(float f0, float f1, float f2, float f3) {
#if __has_builtin(__builtin_amdgcn_cvt_pk_fp8_f32)
    int pk = __builtin_amdgcn_cvt_pk_fp8_f32(f0, f1, 0, false);
    pk = __builtin_amdgcn_cvt_pk_fp8_f32(f2, f3, pk, true);
    return (unsigned)pk;
#else
    return (unsigned)f32_to_e4m3_sw(f0) | ((unsigned)f32_to_e4m3_sw(f1) << 8) |
           ((unsigned)f32_to_e4m3_sw(f2) << 16) | ((unsigned)f32_to_e4m3_sw(f3) << 24);
#endif
}

// --- x0 concat -> bf16 (stride 160) + fp8 split: M8[n][32u] + E8[n][8u] ----
__global__ void k_concat(const float* __restrict__ nf, const int* __restrict__ opc,
                         const float* __restrict__ emb, unsigned* __restrict__ x0,
                         unsigned* __restrict__ m8, unsigned* __restrict__ e8,
                         int n) {
    int idx = blockIdx.x * 256 + threadIdx.x;
    if (idx >= n * 40) return;
    int node = idx / 40;
    int u = idx - node * 40;
    float f[4];
#pragma unroll
    for (int j = 0; j < 4; j++) {
        int ft = 4 * u + j;
        float v = 0.f;
        if (ft < 140) v = nf[(size_t)node * 140 + ft];
        else if (ft < 148) v = emb[opc[node] * 8 + (ft - 140)];
        f[j] = v;
    }
    ((uint2*)x0)[idx] = make_uint2(pack2(f[0], f[1]), pack2(f[2], f[3]));
    unsigned enc = fp8x4_enc(f[0], f[1], f[2], f[3]);
    if (u < 32) m8[(size_t)node * 32 + u] = enc;
    else        e8[(size_t)node * 8 + (u - 32)] = enc;
}

// ---------------- bf16 (stride 32 uints) -> fp8 (16 uints) ----------------
__global__ void k_cvt8(const unsigned* __restrict__ xb, unsigned* __restrict__ x8,
                       int n) {
    int idx = blockIdx.x * 256 + threadIdx.x;
    if (idx >= n * 16) return;
    uint2 v = ((const uint2*)xb)[idx];
    float2 ab = up2(v.x);
    float2 cd = up2(v.y);
    x8[idx] = fp8x4_enc(ab.x, ab.y, cd.x, cd.y);
}

// ---------------- bucketed CSR build ----------------
__global__ __launch_bounds__(256) void k_bh(const int* __restrict__ ei, int E,
                                            int NBUCK, int* __restrict__ bcnt) {
    __shared__ int h[1024];
    int t = threadIdx.x;
    for (int i = t; i < 1024; i += 256) h[i] = 0;
    __syncthreads();
    int e0 = blockIdx.x * 4096, e1 = min(E, e0 + 4096);
    for (int e = e0 + t; e < e1; e += 256) {
        int a = ei[2 * e], b = ei[2 * e + 1];
        atomicAdd(&h[b >> 7], 1);
        atomicAdd(&h[a >> 7], 1);
    }
    __syncthreads();
    for (int i = t; i < NBUCK; i += 256)
        if (h[i]) atomicAdd(&bcnt[i], h[i]);
}

__global__ void k_bscan(const int* __restrict__ bcnt, int NBUCK,
                        int* __restrict__ bo, int* __restrict__ bfill) {
    __shared__ int sm[1024];
    int t = threadIdx.x;
    int v = (t < NBUCK) ? bcnt[t] : 0;
    sm[t] = v;
    __syncthreads();
    for (int off = 1; off < 1024; off <<= 1) {
        int u = 0;
        if (t >= off) u = sm[t - off];
        __syncthreads();
        sm[t] += u;
        __syncthreads();
    }
    if (t < NBUCK) {
        int ex = sm[t] - v;
        bo[t] = ex;
        bfill[t] = ex;
    }
    if (t == NBUCK - 1) bo[NBUCK] = sm[t];
}

__global__ __launch_bounds__(256) void k_bscatter(const int* __restrict__ ei, int E,
                                                  int* __restrict__ bfill,
                                                  uint2* __restrict__ pairs) {
    __shared__ int hist[1024], lbo[1024], gb[1024], cur[1024];
    __shared__ int wsum[4];
    __shared__ int stageD[8192];
    __shared__ int stageS[8192];
    int t = threadIdx.x;
    for (int i = t; i < 1024; i += 256) hist[i] = 0;
    __syncthreads();
    int e0 = blockIdx.x * 4096, e1 = min(E, e0 + 4096);
    for (int e = e0 + t; e < e1; e += 256) {
        int a = ei[2 * e], b = ei[2 * e + 1];
        atomicAdd(&hist[b >> 7], 1);
        atomicAdd(&hist[a >> 7], 1);
    }
    __syncthreads();
    int b4 = t * 4;
    int c0 = hist[b4], c1 = hist[b4 + 1], c2 = hist[b4 + 2], c3 = hist[b4 + 3];
    int ms = c0 + c1 + c2 + c3;
    int lane = t & 63, wv = t >> 6;
    int v = ms;
#pragma unroll
    for (int off = 1; off < 64; off <<= 1) {
        int u = __shfl_up(v, off, 64);
        if (lane >= off) v += u;
    }
    if (lane == 63) wsum[wv] = v;
    __syncthreads();
    int wb = 0;
    for (int i = 0; i < wv; i++) wb += wsum[i];
    int ex = wb + v - ms;
    lbo[b4] = ex;
    lbo[b4 + 1] = ex + c0;
    lbo[b4 + 2] = ex + c0 + c1;
    lbo[b4 + 3] = ex + c0 + c1 + c2;
    if (c0) gb[b4 + 0] = atomicAdd(&bfill[b4 + 0], c0);
    if (c1) gb[b4 + 1] = atomicAdd(&bfill[b4 + 1], c1);
    if (c2) gb[b4 + 2] = atomicAdd(&bfill[b4 + 2], c2);
    if (c3) gb[b4 + 3] = atomicAdd(&bfill[b4 + 3], c3);
    cur[b4] = 0;
    cur[b4 + 1] = 0;
    cur[b4 + 2] = 0;
    cur[b4 + 3] = 0;
    __syncthreads();
    for (int e = e0 + t; e < e1; e += 256) {
        int a = ei[2 * e], b = ei[2 * e + 1];
        int bk = b >> 7;
        int r = atomicAdd(&cur[bk], 1);
        int p = lbo[bk] + r;
        stageD[p] = b;
        stageS[p] = a;
        bk = a >> 7;
        r = atomicAdd(&cur[bk], 1);
        p = lbo[bk] + r;
        stageD[p] = a;
        stageS[p] = b;
    }
    __syncthreads();
    int tot = 2 * (e1 - e0);
    for (int i = t; i < tot; i += 256) {
        int d = stageD[i];
        int bk = d >> 7;
        pairs[gb[bk] + (i - lbo[bk])] = make_uint2((unsigned)d, (unsigned)stageS[i]);
    }
}

__global__ __launch_bounds__(256) void k_bfinal(const uint2* __restrict__ pairs,
                                                const int* __restrict__ bo,
                                                int* __restrict__ rp,
                                                int* __restrict__ csr,
                                                float* __restrict__ invd,
                                                int N, int NBUCK) {
    __shared__ int hist[128], ls[128], cur[128];
    __shared__ unsigned outS[6144];
    int t = threadIdx.x;
    int bk = blockIdx.x;
    int n0 = bk << 7;
    int nn = min(128, N - n0);
    int base = bo[bk], cnt = bo[bk + 1] - base;
    if (t < 128) {
        hist[t] = 0;
        cur[t] = 0;
    }
    __syncthreads();
    for (int i = t; i < cnt; i += 256) atomicAdd(&hist[(int)pairs[base + i].x - n0], 1);
    __syncthreads();
    if (t == 0) {
        int run = 0;
        for (int i = 0; i < 128; i++) {
            ls[i] = run;
            run += hist[i];
        }
    }
    __syncthreads();
    if (t < nn) {
        int node = n0 + t;
        rp[node] = base + ls[t];
        invd[node] = 1.0f / fmaxf((float)hist[t], 1.0f);
    }
    if (bk == NBUCK - 1 && t == 0) rp[N] = base + cnt;
    bool inl = (cnt <= 6144);
    for (int i = t; i < cnt; i += 256) {
        uint2 pr = pairs[base + i];
        int loc = (int)pr.x - n0;
        int r = atomicAdd(&cur[loc], 1);
        int pos = ls[loc] + r;
        if (inl) outS[pos] = pr.y;
        else csr[base + pos] = (int)pr.y;
    }
    __syncthreads();
    if (inl)
        for (int i = t; i < cnt; i += 256) csr[base + i] = (int)outS[i];
}

// ------- layer-0 aggregation: M8 (128B rows, 2 lines) + E8 (32B, L2-hot) ---
__global__ __launch_bounds__(256) void k_agg160(
    const unsigned* __restrict__ m8, const unsigned* __restrict__ e8,
    const int* __restrict__ rp, const int* __restrict__ csr,
    const float* __restrict__ invd, unsigned* __restrict__ agg, int n) {
    int wave = threadIdx.x >> 6;
    int l = threadIdx.x & 63;
    int node = blockIdx.x * 4 + wave;
    if (node >= n) return;
    int p = l & 31;
    int h = l >> 5;
    int eg = l >> 3;
    int eq = l & 7;
    float am[4] = {0.f, 0.f, 0.f, 0.f};
    float ae[4] = {0.f, 0.f, 0.f, 0.f};
    int s = rp[node], e2 = rp[node + 1];
    int j = s;
    for (; j + 8 <= e2; j += 8) {
#pragma unroll
        for (int i = 0; i < 4; i++) {
            int u = csr[j + 2 * i + h];
            unsigned v = m8[(size_t)u * 32 + p];
            floatx2 lo = fp8x2_dec<false>(v);
            floatx2 hi = fp8x2_dec<true>(v);
            am[0] += lo.x;
            am[1] += lo.y;
            am[2] += hi.x;
            am[3] += hi.y;
        }
        int ue = csr[j + eg];
        unsigned v = e8[(size_t)ue * 8 + eq];
        floatx2 lo = fp8x2_dec<false>(v);
        floatx2 hi = fp8x2_dec<true>(v);
        ae[0] += lo.x;
        ae[1] += lo.y;
        ae[2] += hi.x;
        ae[3] += hi.y;
    }
    for (; j < e2; j++) {
        int u = csr[j];
        if (l < 32) {
            unsigned v = m8[(size_t)u * 32 + p];
            floatx2 lo = fp8x2_dec<false>(v);
            floatx2 hi = fp8x2_dec<true>(v);
            am[0] += lo.x;
            am[1] += lo.y;
            am[2] += hi.x;
            am[3] += hi.y;
        } else if (l < 40) {
            unsigned v = e8[(size_t)u * 8 + eq];
            floatx2 lo = fp8x2_dec<false>(v);
            floatx2 hi = fp8x2_dec<true>(v);
            ae[0] += lo.x;
            ae[1] += lo.y;
            ae[2] += hi.x;
            ae[3] += hi.y;
        }
    }
#pragma unroll
    for (int r = 0; r < 4; r++) am[r] += __shfl_xor(am[r], 32, 64);
#pragma unroll
    for (int r = 0; r < 4; r++) {
        ae[r] += __shfl_xor(ae[r], 8, 64);
        ae[r] += __shfl_xor(ae[r], 16, 64);
        ae[r] += __shfl_xor(ae[r], 32, 64);
    }
    float iv = invd[node];
    unsigned* row = agg + (size_t)node * 80;
    if (l < 32)
        ((uint2*)row)[p] = make_uint2(pack2(am[0] * iv, am[1] * iv),
                                      pack2(am[2] * iv, am[3] * iv));
    if (l < 8)
        ((uint2*)(row + 64))[eq] = make_uint2(pack2(ae[0] * iv, ae[1] * iv),
                                              pack2(ae[2] * iv, ae[3] * iv));
}

// ---------------- 64-dim aggregation from fp8 rows (16 uints = 1 line) -----
__global__ __launch_bounds__(256) void k_agg64_8(
    const unsigned* __restrict__ x8, const int* __restrict__ rp,
    const int* __restrict__ csr, const float* __restrict__ invd,
    unsigned* __restrict__ agg, int n) {
    int wave = threadIdx.x >> 6;
    int l = threadIdx.x & 63;
    int node = blockIdx.x * 4 + wave;
    if (node >= n) return;
    int p = l & 15;
    int g = l >> 4;
    float a[4] = {0.f, 0.f, 0.f, 0.f};
    int s = rp[node], e2 = rp[node + 1];
    int j = s;
    for (; j + 16 <= e2; j += 16) {
        unsigned v[4];
#pragma unroll
        for (int i = 0; i < 4; i++) {
            int u = csr[j + 4 * i + g];
            v[i] = x8[(size_t)u * 16 + p];
        }
#pragma unroll
        for (int i = 0; i < 4; i++) {
            floatx2 lo = fp8x2_dec<false>(v[i]);
            floatx2 hi = fp8x2_dec<true>(v[i]);
            a[0] += lo.x;
            a[1] += lo.y;
            a[2] += hi.x;
            a[3] += hi.y;
        }
    }
    for (; j + 8 <= e2; j += 8) {
        int u0 = csr[j + g];
        int u1 = csr[j + 4 + g];
        unsigned v0 = x8[(size_t)u0 * 16 + p];
        unsigned v1 = x8[(size_t)u1 * 16 + p];
        floatx2 lo0 = fp8x2_dec<false>(v0);
        floatx2 hi0 = fp8x2_dec<true>(v0);
        floatx2 lo1 = fp8x2_dec<false>(v1);
        floatx2 hi1 = fp8x2_dec<true>(v1);
        a[0] += lo0.x + lo1.x;
        a[1] += lo0.y + lo1.y;
        a[2] += hi0.x + hi1.x;
        a[3] += hi0.y + hi1.y;
    }
    for (; j < e2; j += 4) {
        if (j + g < e2) {
            int u = csr[j + g];
            unsigned v = x8[(size_t)u * 16 + p];
            floatx2 lo = fp8x2_dec<false>(v);
            floatx2 hi = fp8x2_dec<true>(v);
            a[0] += lo.x;
            a[1] += lo.y;
            a[2] += hi.x;
            a[3] += hi.y;
        }
    }
#pragma unroll
    for (int r = 0; r < 4; r++) {
        a[r] += __shfl_xor(a[r], 16, 64);
        a[r] += __shfl_xor(a[r], 32, 64);
    }
    if (l < 16) {
        float iv = invd[node];
        ((uint2*)(agg + (size_t)node * 32))[p] =
            make_uint2(pack2(a[0] * iv, a[1] * iv), pack2(a[2] * iv, a[3] * iv));
    }
}

// ---------------- weight pre-pack into B-fragment order --------------------
template <int KS, int KSH, int CT, int C>
__global__ void k_prep(const float* __restrict__ W1, const float* __restrict__ W2,
                       int K1, int K2, uint4* __restrict__ Wp) {
    int idx = blockIdx.x * 256 + threadIdx.x;
    if (idx >= CT * KS * 64) return;
    int l = idx & 63;
    int ks = (idx >> 6) % KS;
    int ct = idx / (KS * 64);
    int col = ct * 16 + (l & 15);
    int kbase = ks * 32 + (l >> 4) * 8;
    unsigned short v[8];
#pragma unroll
    for (int j = 0; j < 8; j++) {
        int k = kbase + j;
        float f = 0.f;
        if (col < C) {
            if (k < KSH * 32) {
                if (k < K1) f = W1[(size_t)k * C + col];
            } else {
                int k2 = k - KSH * 32;
                if (k2 < K2) f = W2[(size_t)k2 * C + col];
            }
        }
        v[j] = (unsigned short)bf16_rn(f);
    }
    uint4 o;
    o.x = v[0] | ((unsigned)v[1] << 16);
    o.y = v[2] | ((unsigned)v[3] << 16);
    o.z = v[4] | ((unsigned)v[5] << 16);
    o.w = v[6] | ((unsigned)v[7] << 16);
    Wp[idx] = o;
}

// ---------------- MFMA GEMM (RF=1): out = post([A|B] @ Wp + bias) ----------
template <int KS, int KSH, int CT, int C, int OST, int NORM, int ACT, int OUTF>
__global__ __launch_bounds__(256) void k_gemm(
    const uint4* __restrict__ A, const uint4* __restrict__ Bb,
    const uint4* __restrict__ Wp, const float* __restrict__ bias,
    void* __restrict__ outv, int n) {
    int l = threadIdx.x & 63;
    int wv = threadIdx.x >> 6;
    int rb = blockIdx.x * 64 + wv * 16;
    int rowA = rb + (l & 15);
    if (rowA >= n) rowA = n - 1;           // clamp; stores are guarded
    int koct = l >> 4;
    const int strideU = KSH * 4;           // uint4 per row
    size_t baseA = (size_t)rowA * strideU + koct;

    f32x4 acc[CT];
#pragma unroll
    for (int ct = 0; ct < CT; ct++) acc[ct] = (f32x4){0.f, 0.f, 0.f, 0.f};

#pragma unroll
    for (int ks = 0; ks < KS; ks++) {
        U4B8 a;
        a.u = (ks < KSH) ? A[baseA + ks * 4] : Bb[baseA + (ks - KSH) * 4];
#pragma unroll
        for (int ct = 0; ct < CT; ct++) {
            U4B8 b;
            b.u = Wp[(ct * KS + ks) * 64 + l];
            acc[ct] = __builtin_amdgcn_mfma_f32_16x16x32_bf16(a.b, b.b, acc[ct], 0, 0, 0);
        }
    }

    int cid = l & 15;
    int grp = l >> 4;
#pragma unroll
    for (int ct = 0; ct < CT; ct++) {
        int col = ct * 16 + cid;
        float bv = (col < C) ? bias[col] : 0.f;
#pragma unroll
        for (int r = 0; r < 4; r++) acc[ct][r] += bv;
    }

    if (NORM) {
        float ss[4];
#pragma unroll
        for (int r = 0; r < 4; r++) {
            ss[r] = 0.f;
#pragma unroll
            for (int ct = 0; ct < CT; ct++) ss[r] += acc[ct][r] * acc[ct][r];
        }
#pragma unroll
        for (int off = 1; off < 16; off <<= 1) {
#pragma unroll
            for (int r = 0; r < 4; r++) ss[r] += __shfl_xor(ss[r], off, 64);
        }
#pragma unroll
        for (int r = 0; r < 4; r++) {
            float sc = 1.0f / fmaxf(sqrtf(ss[r]), 1e-12f);
#pragma unroll
            for (int ct = 0; ct < CT; ct++) acc[ct][r] *= sc;
        }
    }

    if (ACT) {
#pragma unroll
        for (int ct = 0; ct < CT; ct++)
#pragma unroll
            for (int r = 0; r < 4; r++) acc[ct][r] = LRELU(acc[ct][r]);
    }

#pragma unroll
    for (int r = 0; r < 4; r++) {
        int row = rb + grp * 4 + r;
        if (row >= n) continue;
        if (OUTF) {
            float* o = (float*)outv;
#pragma unroll
            for (int ct = 0; ct < CT; ct++) {
                int col = ct * 16 + cid;
                if (col < OST) o[(size_t)row * OST + col] = acc[ct][r];
            }
        } else {
            unsigned short* o = (unsigned short*)outv;
#pragma unroll
            for (int ct = 0; ct < CT; ct++) {
                int col = ct * 16 + cid;
                if (col < OST) o[(size_t)row * OST + col] = (unsigned short)bf16_rn(acc[ct][r]);
            }
        }
    }
}

// ---------------- global add-pool: wave per 64 rows, coalesced -------------
__global__ __launch_bounds__(256) void k_pool(const float* __restrict__ x,
                                              const int* __restrict__ batch,
                                              float* __restrict__ g, int n) {
    __shared__ float sm[8][64];
    __shared__ int sb[8];
    int lane = threadIdx.x & 63;
    int wv = threadIdx.x >> 6;
    int base = blockIdx.x * 256 + wv * 64;
    float a0 = 0.f, a1 = 0.f;
    int b0 = -1, b1 = -1;
    int end = (base + 64 < n) ? base + 64 : n;
    for (int row = base; row < end; row++) {
        int bg = batch[row];
        float v = x[(size_t)row * 64 + lane];
        if (b0 < 0) b0 = bg;
        if (bg == b0) a0 += v;
        else { if (b1 < 0) b1 = bg; a1 += v; }
    }
    sm[wv * 2 + 0][lane] = a0;
    sm[wv * 2 + 1][lane] = a1;
    if (lane == 0) {
        sb[wv * 2 + 0] = b0;
        sb[wv * 2 + 1] = b1;
    }
    __syncthreads();
    if (wv == 0) {
        float c0 = 0.f, c1 = 0.f;
        int d0 = -1, d1 = -1;
#pragma unroll
        for (int s = 0; s < 8; s++) {
            int bg = sb[s];
            if (bg < 0) continue;
            float v = sm[s][lane];
            if (d0 < 0) d0 = bg;
            if (bg == d0) c0 += v;
            else { if (d1 < 0) d1 = bg; c1 += v; }
        }
        if (d0 >= 0) atomicAdd(&g[d0 * 64 + lane], c0);
        if (d1 >= 0) atomicAdd(&g[d1 * 64 + lane], c1);
    }
}

// ---------------- post MLP ----------------
__global__ void k_post1(const float* __restrict__ g, const float* __restrict__ cf,
                        const int* __restrict__ ncfg, const float* __restrict__ w1,
                        const float* __restrict__ b1, float* __restrict__ z,
                        int BC, int B) {
    int idx = blockIdx.x * 256 + threadIdx.x;
    if (idx >= BC * 64) return;
    int row = idx >> 6, c = idx & 63;
    int gsum = 0, gid = B - 1;
    for (int b2 = 0; b2 < B; b2++) {
        int ns = ncfg[b2];
        if (row < gsum + ns) { gid = b2; break; }
        gsum += ns;
    }
    float acc = b1[c];
#pragma unroll 4
    for (int k = 0; k < 64; k++) acc += g[gid * 64 + k] * w1[k * 64 + c];
#pragma unroll 4
    for (int k = 0; k < 24; k++) acc += cf[(size_t)row * 24 + k] * w1[(64 + k) * 64 + c];
    z[idx] = LRELU(acc);
}

__global__ void k_post2(const float* __restrict__ z, const float* __restrict__ w2,
                        const float* __restrict__ b2, float* __restrict__ out, int BC) {
    int row = blockIdx.x * 4 + (threadIdx.x >> 6);
    if (row >= BC) return;
    int c = threadIdx.x & 63;
    float v = z[(size_t)row * 64 + c] * w2[c];
#pragma unroll
    for (int off = 32; off > 0; off >>= 1) v += __shfl_xor(v, off, 64);
    if (c == 0) out[row] = v + b2[0];
}

// ---------------------------------------------------------------------------
extern "C" void kernel_launch(void* const* d_in, const int* in_sizes, int n_in,
                              void* d_out, int out_size, void* d_ws, size_t ws_size,
                              hipStream_t stream) {
    const float* node_feat = (const float*)d_in[0];
    const int*   opcode    = (const int*)d_in[1];
    const int*   ei        = (const int*)d_in[2];
    const float* cf        = (const float*)d_in[3];
    const int*   ncfg      = (const int*)d_in[4];
    const int*   batch     = (const int*)d_in[5];
    const float* emb       = (const float*)d_in[6];
    const float* wl0 = (const float*)d_in[7];
    const float* bl0 = (const float*)d_in[8];
    const float* wr0 = (const float*)d_in[9];
    const float* lw0 = (const float*)d_in[10];
    const float* lb0 = (const float*)d_in[11];
    const float* wl1 = (const float*)d_in[12];
    const float* bl1 = (const float*)d_in[13];
    const float* wr1 = (const float*)d_in[14];
    const float* lw1 = (const float*)d_in[15];
    const float* lb1 = (const float*)d_in[16];
    const float* wl2 = (const float*)d_in[17];
    const float* bl2 = (const float*)d_in[18];
    const float* wr2 = (const float*)d_in[19];
    const float* lw2 = (const float*)d_in[20];
    const float* lb2 = (const float*)d_in[21];
    const float* pw1 = (const float*)d_in[22];
    const float* pb1 = (const float*)d_in[23];
    const float* pw2 = (const float*)d_in[24];
    const float* pb2 = (const float*)d_in[25];

    const int N  = in_sizes[0] / 140;
    const int E  = in_sizes[2] / 2;
    const int B  = in_sizes[4];
    const int BC = in_sizes[3] / 24;
    const int NBUCK = (N + 127) >> 7;

    char* w = (char*)d_ws;
    auto alloc = [&](size_t bytes) {
        void* p = (void*)w;
        w += (bytes + 255) & ~(size_t)255;
        return p;
    };
    int*      bcnt     = (int*)alloc(1024 * 4);
    int*      bo       = (int*)alloc(1025 * 4);
    int*      bfill    = (int*)alloc(1024 * 4);
    uint2*    pairs    = (uint2*)alloc((size_t)2 * E * 8);   // dead after k_bfinal
    int*      rp       = (int*)alloc((size_t)(N + 1) * 4);
    float*    invd     = (float*)alloc((size_t)N * 4);
    int*      csr      = (int*)alloc((size_t)2 * E * 4);
    unsigned* X0       = (unsigned*)alloc((size_t)N * 80 * 4);   // bf16, stride 160
    unsigned* AG0      = (unsigned*)alloc((size_t)N * 80 * 4);
    unsigned* H0       = (unsigned*)alloc((size_t)N * 80 * 4);
    unsigned* T0       = (unsigned*)alloc((size_t)N * 32 * 4);   // bf16, stride 64
    unsigned* T1       = (unsigned*)alloc((size_t)N * 32 * 4);
    unsigned* T2       = (unsigned*)alloc((size_t)N * 32 * 4);
    unsigned* G8       = (unsigned*)alloc((size_t)N * 16 * 4);   // fp8 64-dim gather buf
    float*    X3F      = (float*)alloc((size_t)N * 64 * 4);      // final x, f32
    float*    gbuf     = (float*)alloc((size_t)B * 64 * 4);
    float*    zp       = (float*)alloc((size_t)BC * 64 * 4);
    uint4*    Wp0h     = (uint4*)alloc((size_t)10 * 10 * 64 * 16);
    uint4*    Wp0l     = (uint4*)alloc((size_t)4 * 10 * 64 * 16);
    uint4*    Wp1h     = (uint4*)alloc((size_t)4 * 4 * 64 * 16);
    uint4*    Wp1l     = (uint4*)alloc((size_t)4 * 4 * 64 * 16);
    uint4*    Wp2h     = (uint4*)alloc((size_t)4 * 4 * 64 * 16);
    uint4*    Wp2l     = (uint4*)alloc((size_t)4 * 4 * 64 * 16);
    // fp8 x0 split copy (M8: N*32u = 12.8MB, E8: N*8u = 3.2MB) aliases pairs
    // (25.6MB), dead once k_bfinal has run (k_concat launches after it).
    unsigned* M8       = (unsigned*)pairs;
    unsigned* E8       = M8 + (size_t)N * 32;
    (void)ws_size; (void)n_in; (void)out_size;

    (void)hipMemsetAsync(bcnt, 0, 1024 * 4, stream);
    (void)hipMemsetAsync(gbuf, 0, (size_t)B * 64 * 4, stream);

    // weight pre-pack (tiny)
    k_prep<10, 5, 10, 148><<<(6400 + 255) / 256, 256, 0, stream>>>(wl0, wr0, 148, 148, Wp0h);
    k_prep<10, 5, 4, 64><<<(2560 + 255) / 256, 256, 0, stream>>>(lw0, lw0 + 148 * 64, 148, 148, Wp0l);
    k_prep<4, 2, 4, 64><<<4, 256, 0, stream>>>(wl1, wr1, 64, 64, Wp1h);
    k_prep<4, 2, 4, 64><<<4, 256, 0, stream>>>(lw1, lw1 + 64 * 64, 64, 64, Wp1l);
    k_prep<4, 2, 4, 64><<<4, 256, 0, stream>>>(wl2, wr2, 64, 64, Wp2h);
    k_prep<4, 2, 4, 64><<<4, 256, 0, stream>>>(lw2, lw2 + 64 * 64, 64, 64, Wp2l);

    // bucketed CSR build (before k_concat: M8/E8 alias pairs)
    const int EB = (E + 4095) / 4096;
    k_bh<<<EB, 256, 0, stream>>>(ei, E, NBUCK, bcnt);
    k_bscan<<<1, 1024, 0, stream>>>(bcnt, NBUCK, bo, bfill);
    k_bscatter<<<EB, 256, 0, stream>>>(ei, E, bfill, pairs);
    k_bfinal<<<NBUCK, 256, 0, stream>>>(pairs, bo, rp, csr, invd, N, NBUCK);

    k_concat<<<(N * 40 + 255) / 256, 256, 0, stream>>>(node_feat, opcode, emb, X0, M8, E8, N);

    const int AGG_GRID  = (N + 3) / 4;
    const int GEMM_GRID = (N + 63) / 64;
    const int CVT_GRID  = (N * 16 + 255) / 256;

    // ---- layer 0 ----
    k_agg160<<<AGG_GRID, 256, 0, stream>>>(M8, E8, rp, csr, invd, AG0, N);
    k_gemm<10, 5, 10, 148, 160, 1, 0, 0><<<GEMM_GRID, 256, 0, stream>>>(
        (const uint4*)AG0, (const uint4*)X0, Wp0h, bl0, H0, N);
    k_gemm<10, 5, 4, 64, 64, 0, 1, 0><<<GEMM_GRID, 256, 0, stream>>>(
        (const uint4*)H0, (const uint4*)X0, Wp0l, lb0, T0, N);

    // ---- layer 1 ----
    k_cvt8<<<CVT_GRID, 256, 0, stream>>>(T0, G8, N);
    k_agg64_8<<<AGG_GRID, 256, 0, stream>>>(G8, rp, csr, invd, T1, N);
    k_gemm<4, 2, 4, 64, 64, 1, 0, 0><<<GEMM_GRID, 256, 0, stream>>>(
        (const uint4*)T1, (const uint4*)T0, Wp1h, bl1, T2, N);
    k_gemm<4, 2, 4, 64, 64, 0, 1, 0><<<GEMM_GRID, 256, 0, stream>>>(
        (const uint4*)T2, (const uint4*)T0, Wp1l, lb1, T1, N);

    // ---- layer 2 ----
    k_cvt8<<<CVT_GRID, 256, 0, stream>>>(T1, G8, N);
    k_agg64_8<<<AGG_GRID, 256, 0, stream>>>(G8, rp, csr, invd, T0, N);
    k_gemm<4, 2, 4, 64, 64, 1, 0, 0><<<GEMM_GRID, 256, 0, stream>>>(
        (const uint4*)T0, (const uint4*)T1, Wp2h, bl2, T2, N);
    k_gemm<4, 2, 4, 64, 64, 0, 1, 1><<<GEMM_GRID, 256, 0, stream>>>(
        (const uint4*)T2, (const uint4*)T1, Wp2l, lb2, X3F, N);

    // pool + post MLP
    k_pool<<<(N + 255) / 256, 256, 0, stream>>>(X3F, batch, gbuf, N);
    k_post1<<<(BC * 64 + 255) / 256, 256, 0, stream>>>(gbuf, cf, ncfg, pw1, pb1, zp, BC, B);
    k_post2<<<(BC + 3) / 4, 256, 0, stream>>>(zp, pw2, pb2, (float*)d_out, BC);
}